// Round 4
// baseline (221.543 us; speedup 1.0000x reference)
//
#include <hip/hip_runtime.h>
#include <hip/hip_bf16.h>
#include <hip/hip_fp16.h>

typedef _Float16 f16x8  __attribute__((ext_vector_type(8)));
typedef __fp16   h16x2  __attribute__((ext_vector_type(2)));
typedef float    f32x4  __attribute__((ext_vector_type(4)));
typedef float    f32x16 __attribute__((ext_vector_type(16)));

#define KDIM     384
#define MBLK     64
#define PADK     392      // row stride 784 B (16B-aligned, bank offset 4/row)
#define NEDGE    800000
#define WP_ELEMS 49152    // 24 ks * 4 nt * 64 lanes * 8 elems

__device__ __forceinline__ float fast_swish(float v) {
  return v * __builtin_amdgcn_rcpf(1.0f + __expf(-v));
}

__device__ __forceinline__ void pack8(_Float16* dst, float4 a, float4 b) {
  union { h16x2 h[4]; f16x8 v; } u;
  u.h[0] = __builtin_amdgcn_cvt_pkrtz(a.x, a.y);
  u.h[1] = __builtin_amdgcn_cvt_pkrtz(a.z, a.w);
  u.h[2] = __builtin_amdgcn_cvt_pkrtz(b.x, b.y);
  u.h[3] = __builtin_amdgcn_cvt_pkrtz(b.z, b.w);
  *(f16x8*)dst = u.v;
}

// Wp[((ks*4+nt)*64 + l)*8 + e] = W_lin[nt*32 + (l&31)][ks*16 + (l>>5)*8 + e]   (32x32x16 frags)
// Wrp[(nt*64 + l)*8 + e]       = k<6 ? W_rbf[nt*16+(l&15)][k] : 0,  k=(l>>4)*8+e  (16x16x32)
__global__ void pack_w_kernel(const float* __restrict__ W_lin,
                              const float* __restrict__ W_rbf,
                              _Float16* __restrict__ Wp,
                              _Float16* __restrict__ Wrp) {
  int idx = blockIdx.x * 256 + threadIdx.x;
  if (idx < WP_ELEMS) {
    int e  = idx & 7;
    int l  = (idx >> 3) & 63;
    int nt = (idx >> 9) & 3;
    int ks = idx >> 11;                       // 0..23
    int n  = nt * 32 + (l & 31);
    int k  = ks * 16 + ((l >> 5) << 3) + e;
    Wp[idx] = (_Float16)W_lin[n * KDIM + k];
  } else if (idx < WP_ELEMS + 4096) {
    int idx2 = idx - WP_ELEMS;
    int e  = idx2 & 7;
    int l  = (idx2 >> 3) & 63;
    int nt = idx2 >> 9;
    int k  = ((l >> 4) << 3) + e;
    float v = (k < 6) ? W_rbf[(nt * 16 + (l & 15)) * 6 + k] : 0.0f;
    Wrp[idx2] = (_Float16)v;
  }
}

__global__ __launch_bounds__(256, 3)
void embed_main_kernel(const int* __restrict__ x,
                       const float* __restrict__ rbf,
                       const int* __restrict__ gi,
                       const int* __restrict__ gj,
                       const float* __restrict__ resi_w,
                       const float* __restrict__ atom_w,
                       const float* __restrict__ b_rbf,
                       const float* __restrict__ b_lin,
                       const _Float16* __restrict__ Wp,
                       const _Float16* __restrict__ Wrp,
                       float* __restrict__ out) {
  __shared__ alignas(16) _Float16 hlds[MBLK][PADK];
  const int tid  = threadIdx.x;
  const int e0   = blockIdx.x * MBLK;
  const int lane = tid & 63;
  const int wave = tid >> 6;
  const int m    = wave >> 1;        // M-strip (32 rows)
  const int nb   = (wave & 1) * 2;   // first of two 32-col tiles
  const int c5   = lane & 31;
  const int g2   = lane >> 5;

  const f16x8* wp2 = (const f16x8*)Wp + lane;

  // ---- Prologue: issue B chunk 0 (ks 0..5) loads before anything else
  f16x8 breg[2][12];
  #pragma unroll
  for (int q = 0; q < 12; ++q) {
    int ks = q >> 1, ntg = nb + (q & 1);
    breg[0][q] = wp2[(ks * 4 + ntg) * 64];
  }

  // ---- Phase 1a (part 1): index chains
  const int cc  = tid & 15;          // chunk 0..15 (16 f16 each)
  const int seg = cc >> 2;           // 0 resi(i) 1 atom(i) 2 resi(j) 3 atom(j)
  const int off = (cc & 3) << 4;
  const int* __restrict__ gsel = (seg < 2) ? gi : gj;
  const float* __restrict__ tbl = (seg & 1) ? atom_w : resi_w;
  const int m0 = tid >> 4;           // 0..15
  int sel_[4];
  #pragma unroll
  for (int it = 0; it < 4; ++it) {
    int node = gsel[e0 + m0 + it * 16];
    sel_[it] = x[(node << 1) + (seg & 1)];
  }

  // ---- Phase 1b: rbf_h = swish(rbf @ W_rbf^T + b_rbf), 16x16x32 MFMA (K pad 6->32)
  {
    const int g = lane >> 4;         // 16x16 grouping
    const int c = lane & 15;
    f16x8 ra = {0, 0, 0, 0, 0, 0, 0, 0};
    if (g == 0) {
      const float* rp = rbf + (size_t)(e0 + wave * 16 + c) * 6;
      ra[0] = (_Float16)rp[0]; ra[1] = (_Float16)rp[1]; ra[2] = (_Float16)rp[2];
      ra[3] = (_Float16)rp[3]; ra[4] = (_Float16)rp[4]; ra[5] = (_Float16)rp[5];
    }
    const f16x8* wrb = (const f16x8*)Wrp + lane;
    #pragma unroll
    for (int nt = 0; nt < 8; ++nt) {
      f16x8 rb = wrb[nt * 64];
      f32x4 d = __builtin_amdgcn_mfma_f32_16x16x32_f16(ra, rb,
                  (f32x4){0.f, 0.f, 0.f, 0.f}, 0, 0, 0);
      float bb = b_rbf[nt * 16 + c];
      #pragma unroll
      for (int r = 0; r < 4; ++r) {
        float vv = d[r] + bb;
        hlds[wave * 16 + 4 * g + r][256 + nt * 16 + c] = (_Float16)fast_swish(vv);
      }
    }
  }

  // ---- Phase 1a (part 2): embedding rows -> hlds[:, 0:256]
  #pragma unroll
  for (int it = 0; it < 4; ++it) {
    int mm = m0 + it * 16;
    const float4* s4 = (const float4*)(tbl + sel_[it] * 64 + off);
    float4 v0 = s4[0], v1 = s4[1], v2 = s4[2], v3 = s4[3];
    _Float16* dst = &hlds[mm][cc << 4];
    pack8(dst,     v0, v1);
    pack8(dst + 8, v2, v3);
  }
  __syncthreads();

  // ---- Phase 2: 64x384 @ 384x128 via 32x32x16, software-pipelined B in VGPRs
  const _Float16* abase = &hlds[(m << 5) + c5][g2 << 3];

  f32x16 acc0 = {};
  f32x16 acc1 = {};

  #pragma unroll
  for (int chunk = 0; chunk < 4; ++chunk) {
    if (chunk < 3) {
      #pragma unroll
      for (int q = 0; q < 12; ++q) {
        int ks = (chunk + 1) * 6 + (q >> 1), ntg = nb + (q & 1);
        breg[(chunk + 1) & 1][q] = wp2[(ks * 4 + ntg) * 64];
      }
    }
    #pragma unroll
    for (int kl = 0; kl < 6; ++kl) {
      int ks = chunk * 6 + kl;
      f16x8 a = *(const f16x8*)(abase + ks * 16);
      acc0 = __builtin_amdgcn_mfma_f32_32x32x16_f16(a, breg[chunk & 1][kl * 2],     acc0, 0, 0, 0);
      acc1 = __builtin_amdgcn_mfma_f32_32x32x16_f16(a, breg[chunk & 1][kl * 2 + 1], acc1, 0, 0, 0);
    }
  }

  // ---- Epilogue: +bias, swish, store. D: col=lane&31, row=(reg&3)+8*(reg>>2)+4*g2
  const int colA = (wave & 1) * 64 + c5;
  const int colB = colA + 32;
  const float blA = b_lin[colA];
  const float blB = b_lin[colB];
  #pragma unroll
  for (int reg = 0; reg < 16; ++reg) {
    int row = (reg & 3) + 8 * (reg >> 2) + 4 * g2;
    float* orow = out + (size_t)(e0 + (m << 5) + row) * 128;
    orow[colA] = fast_swish(acc0[reg] + blA);
    orow[colB] = fast_swish(acc1[reg] + blB);
  }
}

extern "C" void kernel_launch(void* const* d_in, const int* in_sizes, int n_in,
                              void* d_out, int out_size, void* d_ws, size_t ws_size,
                              hipStream_t stream) {
  const int*   x      = (const int*)d_in[0];
  const float* rbf    = (const float*)d_in[1];
  const int*   gi     = (const int*)d_in[2];
  const int*   gj     = (const int*)d_in[3];
  const float* resi_w = (const float*)d_in[4];
  const float* atom_w = (const float*)d_in[5];
  const float* W_rbf  = (const float*)d_in[6];
  const float* b_rbf  = (const float*)d_in[7];
  const float* W_lin  = (const float*)d_in[8];
  const float* b_lin  = (const float*)d_in[9];
  float* out = (float*)d_out;
  _Float16* Wp  = (_Float16*)d_ws;                 // 96 KB
  _Float16* Wrp = (_Float16*)d_ws + WP_ELEMS;      // + 8 KB

  hipLaunchKernelGGL(pack_w_kernel, dim3(208), dim3(256), 0, stream,
                     W_lin, W_rbf, Wp, Wrp);
  hipLaunchKernelGGL(embed_main_kernel, dim3(NEDGE / MBLK), dim3(256), 0, stream,
                     x, rbf, gi, gj, resi_w, atom_w, b_rbf, b_lin, Wp, Wrp, out);
}